// Round 1
// baseline (937.356 us; speedup 1.0000x reference)
//
#include <hip/hip_runtime.h>

#define F 96

// ---------------- degree / dinv precompute ----------------

__global__ void k_init_deg(float* __restrict__ deg, int N) {
    int i = blockIdx.x * blockDim.x + threadIdx.x;
    if (i < N) deg[i] = 1.0f;  // self-loop
}

__global__ void k_count(const int* __restrict__ dst, float* __restrict__ deg, int E) {
    int e = blockIdx.x * blockDim.x + threadIdx.x;
    if (e < E) atomicAdd(&deg[dst[e]], 1.0f);
}

__global__ void k_rsqrt(float* __restrict__ deg, int N) {
    int i = blockIdx.x * blockDim.x + threadIdx.x;
    if (i < N) deg[i] = rsqrtf(deg[i]);  // in-place: deg -> dinv
}

// ---------------- dense: H = (relu?)(X) @ W ----------------
// 256 threads/block, 64 rows/block. Thread t: cols c2, c2+32, c2+64 (c2=t&31),
// rows rg+8j (rg=t>>5, j=0..7) -> 24 outputs/thread.

template <bool RELU_IN>
__global__ __launch_bounds__(256) void k_dense(const float* __restrict__ X,
                                               const float* __restrict__ W,
                                               float* __restrict__ H, int N) {
    __shared__ float Ws[F][F];    // 36864 B
    __shared__ float Xs[64][F];   // 24576 B
    int t = threadIdx.x;
    for (int i = t; i < F * F; i += 256) ((float*)Ws)[i] = W[i];
    int row0 = blockIdx.x * 64;
    for (int i = t; i < 64 * F; i += 256) {
        int r = i / F, c = i % F;
        int gr = row0 + r;
        float v = (gr < N) ? X[(size_t)gr * F + c] : 0.f;
        if (RELU_IN) v = fmaxf(v, 0.f);
        Xs[r][c] = v;
    }
    __syncthreads();

    int c2 = t & 31;
    int rg = t >> 5;
    float acc[8][3];
#pragma unroll
    for (int j = 0; j < 8; ++j) { acc[j][0] = 0.f; acc[j][1] = 0.f; acc[j][2] = 0.f; }

    for (int k = 0; k < F; ++k) {
        float w0 = Ws[k][c2], w1 = Ws[k][c2 + 32], w2 = Ws[k][c2 + 64];
#pragma unroll
        for (int j = 0; j < 8; ++j) {
            float x = Xs[rg + 8 * j][k];
            acc[j][0] = fmaf(x, w0, acc[j][0]);
            acc[j][1] = fmaf(x, w1, acc[j][1]);
            acc[j][2] = fmaf(x, w2, acc[j][2]);
        }
    }

#pragma unroll
    for (int j = 0; j < 8; ++j) {
        int gr = row0 + rg + 8 * j;
        if (gr < N) {
            float* hp = H + (size_t)gr * F;
            hp[c2]      = acc[j][0];
            hp[c2 + 32] = acc[j][1];
            hp[c2 + 64] = acc[j][2];
        }
    }
}

// ---------------- init: O = H * dinv^2 + b ----------------

__global__ void k_init_out(const float* __restrict__ H, const float* __restrict__ dinv,
                           const float* __restrict__ b, float* __restrict__ O, int N) {
    int idx = blockIdx.x * blockDim.x + threadIdx.x;
    if (idx >= N * F) return;
    int i = idx / F, f = idx % F;
    float di = dinv[i];
    O[idx] = fmaf(H[idx], di * di, b[f]);
}

// ---------------- edge scatter: O[dst] += H[src] * dinv[src]*dinv[dst] ----------------
// 32 threads per edge, 3 features each (coalesced lf + 32j).

__global__ __launch_bounds__(256) void k_scatter(const float* __restrict__ H,
                                                 const int* __restrict__ src,
                                                 const int* __restrict__ dst,
                                                 const float* __restrict__ dinv,
                                                 float* __restrict__ O, int E) {
    int t = blockIdx.x * 256 + threadIdx.x;
    int e = t >> 5;
    if (e >= E) return;
    int lf = t & 31;
    int s = src[e], d = dst[e];
    float nrm = dinv[s] * dinv[d];
    const float* hs = H + (size_t)s * F;
    float* od = O + (size_t)d * F;
#pragma unroll
    for (int j = 0; j < 3; ++j) {
        atomicAdd(&od[lf + 32 * j], hs[lf + 32 * j] * nrm);
    }
}

// ---------------- launch ----------------

extern "C" void kernel_launch(void* const* d_in, const int* in_sizes, int n_in,
                              void* d_out, int out_size, void* d_ws, size_t ws_size,
                              hipStream_t stream) {
    const float* x  = (const float*)d_in[0];
    const float* W1 = (const float*)d_in[1];
    const float* b1 = (const float*)d_in[2];
    const float* W2 = (const float*)d_in[3];
    const float* b2 = (const float*)d_in[4];
    const float* W3 = (const float*)d_in[5];
    const float* b3 = (const float*)d_in[6];
    const int*   ei = (const int*)d_in[7];

    const int N = in_sizes[0] / F;
    const int E = in_sizes[7] / 2;
    const int* src = ei;
    const int* dst = ei + E;

    float* dinv = (float*)d_ws;              // N floats (deg -> dinv in place)
    float* A    = dinv + N;                  // N*F floats (H buffer)
    float* B    = A + (size_t)N * F;         // N*F floats (O1 buffer)
    float* out  = (float*)d_out;             // O2 aliases d_out, final out

    const int thr = 256;
    dim3 blk(thr);
    int gN   = (N + thr - 1) / thr;
    int gE   = (E + thr - 1) / thr;
    int gNF  = (N * F + thr - 1) / thr;
    int gSc  = (E * 32 + thr - 1) / thr;
    int gDen = (N + 63) / 64;

    // degree / dinv (shared across layers)
    k_init_deg<<<gN, blk, 0, stream>>>(dinv, N);
    k_count<<<gE, blk, 0, stream>>>(dst, dinv, E);
    k_rsqrt<<<gN, blk, 0, stream>>>(dinv, N);

    // layer 1: H1 = x@W1 ; O1 = scatter + self + b1   (relu fused into next dense read)
    k_dense<false><<<gDen, blk, 0, stream>>>(x, W1, A, N);
    k_init_out<<<gNF, blk, 0, stream>>>(A, dinv, b1, B, N);
    k_scatter<<<gSc, blk, 0, stream>>>(A, src, dst, dinv, B, E);

    // layer 2: H2 = relu(O1)@W2 ; O2 (= d_out scratch) = scatter + self + b2
    k_dense<true><<<gDen, blk, 0, stream>>>(B, W2, A, N);
    k_init_out<<<gNF, blk, 0, stream>>>(A, dinv, b2, out, N);
    k_scatter<<<gSc, blk, 0, stream>>>(A, src, dst, dinv, out, E);

    // layer 3: H3 = relu(O2)@W3 ; out = scatter + self + b3
    k_dense<true><<<gDen, blk, 0, stream>>>(out, W3, A, N);
    k_init_out<<<gNF, blk, 0, stream>>>(A, dinv, b3, B, N);
    k_scatter<<<gSc, blk, 0, stream>>>(A, src, dst, dinv, B, E);
    // B now holds the final result; copy into d_out
    hipMemcpyAsync(out, B, (size_t)N * F * sizeof(float), hipMemcpyDeviceToDevice, stream);
}

// Round 2
// 386.383 us; speedup vs baseline: 2.4260x; 2.4260x over previous
//
#include <hip/hip_runtime.h>

#define F 96
#define SCAN_B 1024

// ================= CSR build =================

__global__ void k_zero_i(int* __restrict__ p, int n) {
    int i = blockIdx.x * blockDim.x + threadIdx.x;
    if (i < n) p[i] = 0;
}

__global__ void k_hist(const int* __restrict__ dst, int* __restrict__ hist, int E) {
    int e = blockIdx.x * blockDim.x + threadIdx.x;
    if (e < E) atomicAdd(&hist[dst[e]], 1);
}

__global__ void k_dinv(const int* __restrict__ hist, float* __restrict__ dinv, int N) {
    int i = blockIdx.x * blockDim.x + threadIdx.x;
    if (i < N) dinv[i] = rsqrtf((float)hist[i] + 1.0f);  // +1 self-loop
}

// inclusive scan per 1024-block, emit block sums
__global__ __launch_bounds__(SCAN_B) void k_scan1(const int* __restrict__ hist,
                                                  int* __restrict__ incl,
                                                  int* __restrict__ bsum, int N) {
    __shared__ int s[SCAN_B];
    int i = blockIdx.x * SCAN_B + threadIdx.x;
    int v = (i < N) ? hist[i] : 0;
    s[threadIdx.x] = v;
    __syncthreads();
    for (int off = 1; off < SCAN_B; off <<= 1) {
        int add = (threadIdx.x >= off) ? s[threadIdx.x - off] : 0;
        __syncthreads();
        s[threadIdx.x] += add;
        __syncthreads();
    }
    if (i < N) incl[i] = s[threadIdx.x];
    if (threadIdx.x == SCAN_B - 1) bsum[blockIdx.x] = s[SCAN_B - 1];
}

// exclusive scan of block sums (single block; nb <= 1024)
__global__ __launch_bounds__(SCAN_B) void k_scan2(int* __restrict__ bsum, int nb) {
    __shared__ int s[SCAN_B];
    int v = (threadIdx.x < nb) ? bsum[threadIdx.x] : 0;
    s[threadIdx.x] = v;
    __syncthreads();
    for (int off = 1; off < SCAN_B; off <<= 1) {
        int add = (threadIdx.x >= off) ? s[threadIdx.x - off] : 0;
        __syncthreads();
        s[threadIdx.x] += add;
        __syncthreads();
    }
    if (threadIdx.x < nb) bsum[threadIdx.x] = s[threadIdx.x] - v;  // exclusive
}

__global__ void k_scan3(const int* __restrict__ incl, const int* __restrict__ hist,
                        const int* __restrict__ bsum, int* __restrict__ row_ptr,
                        int* __restrict__ cursor, int N, int E) {
    int i = blockIdx.x * blockDim.x + threadIdx.x;
    if (i < N) {
        int start = incl[i] - hist[i] + bsum[i / SCAN_B];
        row_ptr[i] = start;
        cursor[i] = start;
    }
    if (i == 0) row_ptr[N] = E;
}

__global__ void k_place(const int* __restrict__ src, const int* __restrict__ dst,
                        const float* __restrict__ dinv, int* __restrict__ cursor,
                        int* __restrict__ csr_src, float* __restrict__ csr_w, int E) {
    int e = blockIdx.x * blockDim.x + threadIdx.x;
    if (e >= E) return;
    int s = src[e], d = dst[e];
    int pos = atomicAdd(&cursor[d], 1);
    csr_src[pos] = s;
    csr_w[pos] = dinv[s] * dinv[d];
}

// ================= dense: H = (relu?)(X) @ W =================

template <bool RELU_IN>
__global__ __launch_bounds__(256) void k_dense(const float* __restrict__ X,
                                               const float* __restrict__ W,
                                               float* __restrict__ H, int N) {
    __shared__ float Ws[F][F];
    __shared__ float Xs[64][F];
    int t = threadIdx.x;
    for (int i = t; i < F * F; i += 256) ((float*)Ws)[i] = W[i];
    int row0 = blockIdx.x * 64;
    for (int i = t; i < 64 * F; i += 256) {
        int r = i / F, c = i % F;
        int gr = row0 + r;
        float v = (gr < N) ? X[(size_t)gr * F + c] : 0.f;
        if (RELU_IN) v = fmaxf(v, 0.f);
        Xs[r][c] = v;
    }
    __syncthreads();

    int c2 = t & 31;
    int rg = t >> 5;
    float acc[8][3];
#pragma unroll
    for (int j = 0; j < 8; ++j) { acc[j][0] = 0.f; acc[j][1] = 0.f; acc[j][2] = 0.f; }

    for (int k = 0; k < F; ++k) {
        float w0 = Ws[k][c2], w1 = Ws[k][c2 + 32], w2 = Ws[k][c2 + 64];
#pragma unroll
        for (int j = 0; j < 8; ++j) {
            float x = Xs[rg + 8 * j][k];
            acc[j][0] = fmaf(x, w0, acc[j][0]);
            acc[j][1] = fmaf(x, w1, acc[j][1]);
            acc[j][2] = fmaf(x, w2, acc[j][2]);
        }
    }

#pragma unroll
    for (int j = 0; j < 8; ++j) {
        int gr = row0 + rg + 8 * j;
        if (gr < N) {
            float* hp = H + (size_t)gr * F;
            hp[c2]      = acc[j][0];
            hp[c2 + 32] = acc[j][1];
            hp[c2 + 64] = acc[j][2];
        }
    }
}

// ================= gather aggregation =================
// 32 lanes per node; lane handles features lf, lf+32, lf+64.
// O[i] = sum_e w_e * H[src_e] + H[i]*dinv_i^2 + b

__global__ __launch_bounds__(256) void k_gather(const float* __restrict__ H,
                                                const int* __restrict__ csr_src,
                                                const float* __restrict__ csr_w,
                                                const int* __restrict__ row_ptr,
                                                const float* __restrict__ dinv,
                                                const float* __restrict__ b,
                                                float* __restrict__ O, int N) {
    int t = blockIdx.x * 256 + threadIdx.x;
    int node = t >> 5;
    if (node >= N) return;
    int lf = t & 31;
    int s0 = row_ptr[node], s1 = row_ptr[node + 1];
    float di = dinv[node];
    float d2 = di * di;
    const float* hn = H + (size_t)node * F;
    float a0 = fmaf(hn[lf],      d2, b[lf]);
    float a1 = fmaf(hn[lf + 32], d2, b[lf + 32]);
    float a2 = fmaf(hn[lf + 64], d2, b[lf + 64]);

    int e = s0;
    for (; e + 1 < s1; e += 2) {
        int sA = csr_src[e], sB = csr_src[e + 1];
        float wA = csr_w[e], wB = csr_w[e + 1];
        const float* hA = H + (size_t)sA * F;
        const float* hB = H + (size_t)sB * F;
        float xA0 = hA[lf], xA1 = hA[lf + 32], xA2 = hA[lf + 64];
        float xB0 = hB[lf], xB1 = hB[lf + 32], xB2 = hB[lf + 64];
        a0 = fmaf(xA0, wA, a0); a1 = fmaf(xA1, wA, a1); a2 = fmaf(xA2, wA, a2);
        a0 = fmaf(xB0, wB, a0); a1 = fmaf(xB1, wB, a1); a2 = fmaf(xB2, wB, a2);
    }
    if (e < s1) {
        int sA = csr_src[e];
        float wA = csr_w[e];
        const float* hA = H + (size_t)sA * F;
        a0 = fmaf(hA[lf], wA, a0);
        a1 = fmaf(hA[lf + 32], wA, a1);
        a2 = fmaf(hA[lf + 64], wA, a2);
    }

    float* o = O + (size_t)node * F;
    o[lf]      = a0;
    o[lf + 32] = a1;
    o[lf + 64] = a2;
}

// ================= fallback (R1 atomic-scatter path) =================

__global__ void k_init_deg(float* __restrict__ deg, int N) {
    int i = blockIdx.x * blockDim.x + threadIdx.x;
    if (i < N) deg[i] = 1.0f;
}
__global__ void k_count(const int* __restrict__ dst, float* __restrict__ deg, int E) {
    int e = blockIdx.x * blockDim.x + threadIdx.x;
    if (e < E) atomicAdd(&deg[dst[e]], 1.0f);
}
__global__ void k_rsqrt(float* __restrict__ deg, int N) {
    int i = blockIdx.x * blockDim.x + threadIdx.x;
    if (i < N) deg[i] = rsqrtf(deg[i]);
}
__global__ void k_init_out(const float* __restrict__ H, const float* __restrict__ dinv,
                           const float* __restrict__ b, float* __restrict__ O, int N) {
    int idx = blockIdx.x * blockDim.x + threadIdx.x;
    if (idx >= N * F) return;
    int i = idx / F, f = idx % F;
    float di = dinv[i];
    O[idx] = fmaf(H[idx], di * di, b[f]);
}
__global__ __launch_bounds__(256) void k_scatter(const float* __restrict__ H,
                                                 const int* __restrict__ src,
                                                 const int* __restrict__ dst,
                                                 const float* __restrict__ dinv,
                                                 float* __restrict__ O, int E) {
    int t = blockIdx.x * 256 + threadIdx.x;
    int e = t >> 5;
    if (e >= E) return;
    int lf = t & 31;
    int s = src[e], d = dst[e];
    float nrm = dinv[s] * dinv[d];
    const float* hs = H + (size_t)s * F;
    float* od = O + (size_t)d * F;
#pragma unroll
    for (int j = 0; j < 3; ++j) atomicAdd(&od[lf + 32 * j], hs[lf + 32 * j] * nrm);
}

// ================= launch =================

extern "C" void kernel_launch(void* const* d_in, const int* in_sizes, int n_in,
                              void* d_out, int out_size, void* d_ws, size_t ws_size,
                              hipStream_t stream) {
    const float* x  = (const float*)d_in[0];
    const float* W1 = (const float*)d_in[1];
    const float* b1 = (const float*)d_in[2];
    const float* W2 = (const float*)d_in[3];
    const float* b2 = (const float*)d_in[4];
    const float* W3 = (const float*)d_in[5];
    const float* b3 = (const float*)d_in[6];
    const int*   ei = (const int*)d_in[7];

    const int N = in_sizes[0] / F;
    const int E = in_sizes[7] / 2;
    const int* src = ei;
    const int* dst = ei + E;
    const size_t NF = (size_t)N * F;

    const int thr = 256;
    dim3 blk(thr);
    int gN  = (N + thr - 1) / thr;
    int gE  = (E + thr - 1) / thr;
    int gDen = (N + 63) / 64;
    int gGat = (N * 32 + thr - 1) / thr;
    int nScanB = (N + SCAN_B - 1) / SCAN_B;

    // ---- workspace layout (CSR path) ----
    float* dinv    = (float*)d_ws;                 // N
    int*   row_ptr = (int*)(dinv + N);             // N+1
    int*   csr_src = row_ptr + N + 1;              // E
    float* csr_w   = (float*)(csr_src + E);        // E
    float* A       = csr_w + E;                    // N*F
    float* B       = A + NF;                       // N*F
    // temps aliased into A/B (dead before dense/gather touch them)
    int* hist   = (int*)A;                         // N
    int* incl   = hist + N;                        // N
    int* cursor = (int*)B;                         // N
    int* bsum   = cursor + N;                      // <=1024

    size_t need = ((size_t)N + (N + 1) + 2 * (size_t)E + 2 * NF) * 4;
    float* out = (float*)d_out;

    if (ws_size >= need && nScanB <= SCAN_B) {
        // ---- CSR build (once; reused by all 3 layers) ----
        k_zero_i<<<gN, blk, 0, stream>>>(hist, N);
        k_hist<<<gE, blk, 0, stream>>>(dst, hist, E);
        k_dinv<<<gN, blk, 0, stream>>>(hist, dinv, N);
        k_scan1<<<nScanB, dim3(SCAN_B), 0, stream>>>(hist, incl, bsum, N);
        k_scan2<<<1, dim3(SCAN_B), 0, stream>>>(bsum, nScanB);
        k_scan3<<<gN, blk, 0, stream>>>(incl, hist, bsum, row_ptr, cursor, N, E);
        k_place<<<gE, blk, 0, stream>>>(src, dst, dinv, cursor, csr_src, csr_w, E);

        // ---- layer 1 ----
        k_dense<false><<<gDen, blk, 0, stream>>>(x, W1, A, N);
        k_gather<<<gGat, blk, 0, stream>>>(A, csr_src, csr_w, row_ptr, dinv, b1, B, N);
        // ---- layer 2 ----
        k_dense<true><<<gDen, blk, 0, stream>>>(B, W2, A, N);
        k_gather<<<gGat, blk, 0, stream>>>(A, csr_src, csr_w, row_ptr, dinv, b2, B, N);
        // ---- layer 3 ----
        k_dense<true><<<gDen, blk, 0, stream>>>(B, W3, A, N);
        k_gather<<<gGat, blk, 0, stream>>>(A, csr_src, csr_w, row_ptr, dinv, b3, out, N);
    } else {
        // ---- fallback: R1 atomic-scatter path (needs N + 2NF floats) ----
        float* fA = dinv + N;
        float* fB = fA + NF;
        int gNF = (int)((NF + thr - 1) / thr);
        int gSc = (int)(((size_t)E * 32 + thr - 1) / thr);
        k_init_deg<<<gN, blk, 0, stream>>>(dinv, N);
        k_count<<<gE, blk, 0, stream>>>(dst, dinv, E);
        k_rsqrt<<<gN, blk, 0, stream>>>(dinv, N);
        k_dense<false><<<gDen, blk, 0, stream>>>(x, W1, fA, N);
        k_init_out<<<gNF, blk, 0, stream>>>(fA, dinv, b1, fB, N);
        k_scatter<<<gSc, blk, 0, stream>>>(fA, src, dst, dinv, fB, E);
        k_dense<true><<<gDen, blk, 0, stream>>>(fB, W2, fA, N);
        k_init_out<<<gNF, blk, 0, stream>>>(fA, dinv, b2, out, N);
        k_scatter<<<gSc, blk, 0, stream>>>(fA, src, dst, dinv, out, E);
        k_dense<true><<<gDen, blk, 0, stream>>>(out, W3, fA, N);
        k_init_out<<<gNF, blk, 0, stream>>>(fA, dinv, b3, fB, N);
        k_scatter<<<gSc, blk, 0, stream>>>(fA, src, dst, dinv, fB, E);
        hipMemcpyAsync(out, fB, NF * sizeof(float), hipMemcpyDeviceToDevice, stream);
    }
}

// Round 3
// 360.939 us; speedup vs baseline: 2.5970x; 1.0705x over previous
//
#include <hip/hip_runtime.h>

#define F 96
#define SCAN_B 1024

// Wt[c][k] stored XOR-swizzled so column-of-W reads spread across bank slots.
// (k ^ (4*(c&7))) stays within k's 32-float block since 96 = 3*32.
#define WT_IDX(c, k) ((c) * 96 + (((k) ^ (((c) & 7) << 2))))

// ================= CSR build =================

__global__ void k_zero_i(int* __restrict__ p, int n) {
    int i = blockIdx.x * blockDim.x + threadIdx.x;
    if (i < n) p[i] = 0;
}

__global__ void k_hist(const int* __restrict__ dst, int* __restrict__ hist, int E) {
    int e = blockIdx.x * blockDim.x + threadIdx.x;
    if (e < E) atomicAdd(&hist[dst[e]], 1);
}

__global__ void k_dinv(const int* __restrict__ hist, float* __restrict__ dinv, int N) {
    int i = blockIdx.x * blockDim.x + threadIdx.x;
    if (i < N) dinv[i] = rsqrtf((float)hist[i] + 1.0f);  // +1 self-loop
}

__global__ __launch_bounds__(SCAN_B) void k_scan1(const int* __restrict__ hist,
                                                  int* __restrict__ incl,
                                                  int* __restrict__ bsum, int N) {
    __shared__ int s[SCAN_B];
    int i = blockIdx.x * SCAN_B + threadIdx.x;
    int v = (i < N) ? hist[i] : 0;
    s[threadIdx.x] = v;
    __syncthreads();
    for (int off = 1; off < SCAN_B; off <<= 1) {
        int add = (threadIdx.x >= off) ? s[threadIdx.x - off] : 0;
        __syncthreads();
        s[threadIdx.x] += add;
        __syncthreads();
    }
    if (i < N) incl[i] = s[threadIdx.x];
    if (threadIdx.x == SCAN_B - 1) bsum[blockIdx.x] = s[SCAN_B - 1];
}

__global__ __launch_bounds__(SCAN_B) void k_scan2(int* __restrict__ bsum, int nb) {
    __shared__ int s[SCAN_B];
    int v = (threadIdx.x < nb) ? bsum[threadIdx.x] : 0;
    s[threadIdx.x] = v;
    __syncthreads();
    for (int off = 1; off < SCAN_B; off <<= 1) {
        int add = (threadIdx.x >= off) ? s[threadIdx.x - off] : 0;
        __syncthreads();
        s[threadIdx.x] += add;
        __syncthreads();
    }
    if (threadIdx.x < nb) bsum[threadIdx.x] = s[threadIdx.x] - v;  // exclusive
}

__global__ void k_scan3(const int* __restrict__ incl, const int* __restrict__ hist,
                        const int* __restrict__ bsum, int* __restrict__ row_ptr,
                        int* __restrict__ cursor, int N, int E) {
    int i = blockIdx.x * blockDim.x + threadIdx.x;
    if (i < N) {
        int start = incl[i] - hist[i] + bsum[i / SCAN_B];
        row_ptr[i] = start;
        cursor[i] = start;
    }
    if (i == 0) row_ptr[N] = E;
}

// only src index is materialized; weights recomputed in gather (dinv is L2-resident)
__global__ void k_place(const int* __restrict__ src, const int* __restrict__ dst,
                        int* __restrict__ cursor, int* __restrict__ csr_src, int E) {
    int e = blockIdx.x * blockDim.x + threadIdx.x;
    if (e >= E) return;
    int pos = atomicAdd(&cursor[dst[e]], 1);
    csr_src[pos] = src[e];
}

// ================= dense: H = (relu?)(X) @ W =================
// 256 threads, 64 rows x 96 cols per block. Thread t: cols {c2,c2+32,c2+64}
// (c2=t&31), rows rg+8j (rg=t>>5, j=0..7). k-loop vectorized by 4 (float4 LDS).

template <bool RELU_IN>
__global__ __launch_bounds__(256) void k_dense(const float* __restrict__ X,
                                               const float* __restrict__ W,
                                               float* __restrict__ H, int N) {
    __shared__ float Wt[96 * 96];   // transposed + swizzled, 36 KB
    __shared__ float Xs[64][96];    // 24 KB
    int t = threadIdx.x;
    for (int i = t; i < F * F; i += 256) {
        int k = i / F, c = i % F;
        Wt[WT_IDX(c, k)] = W[i];
    }
    int row0 = blockIdx.x * 64;
    for (int i = t; i < 64 * 24; i += 256) {
        int r = i / 24, c4 = (i % 24) * 4;
        int gr = row0 + r;
        float4 v = make_float4(0.f, 0.f, 0.f, 0.f);
        if (gr < N) {
            v = *reinterpret_cast<const float4*>(X + (size_t)gr * F + c4);
            if (RELU_IN) {
                v.x = fmaxf(v.x, 0.f); v.y = fmaxf(v.y, 0.f);
                v.z = fmaxf(v.z, 0.f); v.w = fmaxf(v.w, 0.f);
            }
        }
        *reinterpret_cast<float4*>(&Xs[r][c4]) = v;
    }
    __syncthreads();

    int c2 = t & 31;
    int rg = t >> 5;
    float acc[8][3];
#pragma unroll
    for (int j = 0; j < 8; ++j) { acc[j][0] = 0.f; acc[j][1] = 0.f; acc[j][2] = 0.f; }

    for (int k4 = 0; k4 < F; k4 += 4) {
        float4 w0 = *reinterpret_cast<const float4*>(&Wt[WT_IDX(c2, k4)]);
        float4 w1 = *reinterpret_cast<const float4*>(&Wt[WT_IDX(c2 + 32, k4)]);
        float4 w2 = *reinterpret_cast<const float4*>(&Wt[WT_IDX(c2 + 64, k4)]);
#pragma unroll
        for (int j = 0; j < 8; ++j) {
            float4 xv = *reinterpret_cast<const float4*>(&Xs[rg + 8 * j][k4]);
            acc[j][0] = fmaf(xv.x, w0.x, acc[j][0]);
            acc[j][1] = fmaf(xv.x, w1.x, acc[j][1]);
            acc[j][2] = fmaf(xv.x, w2.x, acc[j][2]);
            acc[j][0] = fmaf(xv.y, w0.y, acc[j][0]);
            acc[j][1] = fmaf(xv.y, w1.y, acc[j][1]);
            acc[j][2] = fmaf(xv.y, w2.y, acc[j][2]);
            acc[j][0] = fmaf(xv.z, w0.z, acc[j][0]);
            acc[j][1] = fmaf(xv.z, w1.z, acc[j][1]);
            acc[j][2] = fmaf(xv.z, w2.z, acc[j][2]);
            acc[j][0] = fmaf(xv.w, w0.w, acc[j][0]);
            acc[j][1] = fmaf(xv.w, w1.w, acc[j][1]);
            acc[j][2] = fmaf(xv.w, w2.w, acc[j][2]);
        }
    }

#pragma unroll
    for (int j = 0; j < 8; ++j) {
        int gr = row0 + rg + 8 * j;
        if (gr < N) {
            float* hp = H + (size_t)gr * F;
            hp[c2]      = acc[j][0];
            hp[c2 + 32] = acc[j][1];
            hp[c2 + 64] = acc[j][2];
        }
    }
}

// ================= gather aggregation =================
// 32 lanes per node; lane handles features lf, lf+32, lf+64.
// O[i] = sum_e dinv[s]*dinv[i] * H[s] + H[i]*dinv_i^2 + b

__global__ __launch_bounds__(256) void k_gather(const float* __restrict__ H,
                                                const int* __restrict__ csr_src,
                                                const int* __restrict__ row_ptr,
                                                const float* __restrict__ dinv,
                                                const float* __restrict__ b,
                                                float* __restrict__ O, int N) {
    int t = blockIdx.x * 256 + threadIdx.x;
    int node = t >> 5;
    if (node >= N) return;
    int lf = t & 31;
    int s0 = row_ptr[node], s1 = row_ptr[node + 1];
    float di = dinv[node];
    float d2 = di * di;
    const float* hn = H + (size_t)node * F;
    float a0 = fmaf(hn[lf],      d2, b[lf]);
    float a1 = fmaf(hn[lf + 32], d2, b[lf + 32]);
    float a2 = fmaf(hn[lf + 64], d2, b[lf + 64]);

    int e = s0;
    for (; e + 3 < s1; e += 4) {
        int sA = csr_src[e],     sB = csr_src[e + 1];
        int sC = csr_src[e + 2], sD = csr_src[e + 3];
        float wA = dinv[sA] * di, wB = dinv[sB] * di;
        float wC = dinv[sC] * di, wD = dinv[sD] * di;
        const float* hA = H + (size_t)sA * F;
        const float* hB = H + (size_t)sB * F;
        const float* hC = H + (size_t)sC * F;
        const float* hD = H + (size_t)sD * F;
        a0 = fmaf(hA[lf], wA, a0); a1 = fmaf(hA[lf + 32], wA, a1); a2 = fmaf(hA[lf + 64], wA, a2);
        a0 = fmaf(hB[lf], wB, a0); a1 = fmaf(hB[lf + 32], wB, a1); a2 = fmaf(hB[lf + 64], wB, a2);
        a0 = fmaf(hC[lf], wC, a0); a1 = fmaf(hC[lf + 32], wC, a1); a2 = fmaf(hC[lf + 64], wC, a2);
        a0 = fmaf(hD[lf], wD, a0); a1 = fmaf(hD[lf + 32], wD, a1); a2 = fmaf(hD[lf + 64], wD, a2);
    }
    for (; e < s1; ++e) {
        int sA = csr_src[e];
        float wA = dinv[sA] * di;
        const float* hA = H + (size_t)sA * F;
        a0 = fmaf(hA[lf], wA, a0);
        a1 = fmaf(hA[lf + 32], wA, a1);
        a2 = fmaf(hA[lf + 64], wA, a2);
    }

    float* o = O + (size_t)node * F;
    o[lf]      = a0;
    o[lf + 32] = a1;
    o[lf + 64] = a2;
}

// ================= fallback (atomic-scatter path) =================

__global__ void k_init_deg(float* __restrict__ deg, int N) {
    int i = blockIdx.x * blockDim.x + threadIdx.x;
    if (i < N) deg[i] = 1.0f;
}
__global__ void k_count(const int* __restrict__ dst, float* __restrict__ deg, int E) {
    int e = blockIdx.x * blockDim.x + threadIdx.x;
    if (e < E) atomicAdd(&deg[dst[e]], 1.0f);
}
__global__ void k_rsqrt(float* __restrict__ deg, int N) {
    int i = blockIdx.x * blockDim.x + threadIdx.x;
    if (i < N) deg[i] = rsqrtf(deg[i]);
}
__global__ void k_init_out(const float* __restrict__ H, const float* __restrict__ dinv,
                           const float* __restrict__ b, float* __restrict__ O, int N) {
    int idx = blockIdx.x * blockDim.x + threadIdx.x;
    if (idx >= N * F) return;
    int i = idx / F, f = idx % F;
    float di = dinv[i];
    O[idx] = fmaf(H[idx], di * di, b[f]);
}
__global__ __launch_bounds__(256) void k_scatter(const float* __restrict__ H,
                                                 const int* __restrict__ src,
                                                 const int* __restrict__ dst,
                                                 const float* __restrict__ dinv,
                                                 float* __restrict__ O, int E) {
    int t = blockIdx.x * 256 + threadIdx.x;
    int e = t >> 5;
    if (e >= E) return;
    int lf = t & 31;
    int s = src[e], d = dst[e];
    float nrm = dinv[s] * dinv[d];
    const float* hs = H + (size_t)s * F;
    float* od = O + (size_t)d * F;
#pragma unroll
    for (int j = 0; j < 3; ++j) atomicAdd(&od[lf + 32 * j], hs[lf + 32 * j] * nrm);
}

// ================= launch =================

extern "C" void kernel_launch(void* const* d_in, const int* in_sizes, int n_in,
                              void* d_out, int out_size, void* d_ws, size_t ws_size,
                              hipStream_t stream) {
    const float* x  = (const float*)d_in[0];
    const float* W1 = (const float*)d_in[1];
    const float* b1 = (const float*)d_in[2];
    const float* W2 = (const float*)d_in[3];
    const float* b2 = (const float*)d_in[4];
    const float* W3 = (const float*)d_in[5];
    const float* b3 = (const float*)d_in[6];
    const int*   ei = (const int*)d_in[7];

    const int N = in_sizes[0] / F;
    const int E = in_sizes[7] / 2;
    const int* src = ei;
    const int* dst = ei + E;
    const size_t NF = (size_t)N * F;

    const int thr = 256;
    dim3 blk(thr);
    int gN  = (N + thr - 1) / thr;
    int gE  = (E + thr - 1) / thr;
    int gDen = (N + 63) / 64;
    int gGat = (int)(((size_t)N * 32 + thr - 1) / thr);
    int nScanB = (N + SCAN_B - 1) / SCAN_B;

    // ---- workspace layout (CSR path) ----
    float* dinv    = (float*)d_ws;                 // N
    int*   row_ptr = (int*)(dinv + N);             // N+1
    int*   csr_src = row_ptr + N + 1;              // E
    float* A       = (float*)(csr_src + E);        // N*F
    float* B       = A + NF;                       // N*F
    // temps aliased into A/B (dead before dense/gather touch them)
    int* hist   = (int*)A;                         // N
    int* incl   = hist + N;                        // N
    int* cursor = (int*)B;                         // N
    int* bsum   = cursor + N;                      // <=1024

    size_t need = ((size_t)N + (N + 1) + (size_t)E + 2 * NF) * 4;
    float* out = (float*)d_out;

    if (ws_size >= need && nScanB <= SCAN_B) {
        // ---- CSR build (once; reused by all 3 layers) ----
        k_zero_i<<<gN, blk, 0, stream>>>(hist, N);
        k_hist<<<gE, blk, 0, stream>>>(dst, hist, E);
        k_scan1<<<nScanB, dim3(SCAN_B), 0, stream>>>(hist, incl, bsum, N);
        k_scan2<<<1, dim3(SCAN_B), 0, stream>>>(bsum, nScanB);
        k_scan3<<<gN, blk, 0, stream>>>(incl, hist, bsum, row_ptr, cursor, N, E);
        k_dinv<<<gN, blk, 0, stream>>>(hist, dinv, N);   // before A is overwritten
        k_place<<<gE, blk, 0, stream>>>(src, dst, cursor, csr_src, E);

        // ---- layer 1 ----
        k_dense<false><<<gDen, blk, 0, stream>>>(x, W1, A, N);
        k_gather<<<gGat, blk, 0, stream>>>(A, csr_src, row_ptr, dinv, b1, B, N);
        // ---- layer 2 ----
        k_dense<true><<<gDen, blk, 0, stream>>>(B, W2, A, N);
        k_gather<<<gGat, blk, 0, stream>>>(A, csr_src, row_ptr, dinv, b2, B, N);
        // ---- layer 3 ----
        k_dense<true><<<gDen, blk, 0, stream>>>(B, W3, A, N);
        k_gather<<<gGat, blk, 0, stream>>>(A, csr_src, row_ptr, dinv, b3, out, N);
    } else {
        // ---- fallback: atomic-scatter path (needs N + 2NF floats) ----
        float* fdinv = (float*)d_ws;
        float* fA = fdinv + N;
        float* fB = fA + NF;
        int gNF = (int)((NF + thr - 1) / thr);
        int gSc = (int)(((size_t)E * 32 + thr - 1) / thr);
        k_init_deg<<<gN, blk, 0, stream>>>(fdinv, N);
        k_count<<<gE, blk, 0, stream>>>(dst, fdinv, E);
        k_rsqrt<<<gN, blk, 0, stream>>>(fdinv, N);
        k_dense<false><<<gDen, blk, 0, stream>>>(x, W1, fA, N);
        k_init_out<<<gNF, blk, 0, stream>>>(fA, fdinv, b1, fB, N);
        k_scatter<<<gSc, blk, 0, stream>>>(fA, src, dst, fdinv, fB, E);
        k_dense<true><<<gDen, blk, 0, stream>>>(fB, W2, fA, N);
        k_init_out<<<gNF, blk, 0, stream>>>(fA, fdinv, b2, out, N);
        k_scatter<<<gSc, blk, 0, stream>>>(fA, src, dst, fdinv, out, E);
        k_dense<true><<<gDen, blk, 0, stream>>>(out, W3, fA, N);
        k_init_out<<<gNF, blk, 0, stream>>>(fA, fdinv, b3, fB, N);
        k_scatter<<<gSc, blk, 0, stream>>>(fA, src, dst, fdinv, fB, E);
        hipMemcpyAsync(out, fB, NF * sizeof(float), hipMemcpyDeviceToDevice, stream);
    }
}